// Round 4
// baseline (1044.612 us; speedup 1.0000x reference)
//
#include <hip/hip_runtime.h>

typedef float v2f __attribute__((ext_vector_type(2)));

#define TX 64
#define TY 8                 // output rows per chunk
#define MY 8                 // chunks per block
#define BYR (TY * MY)        // 64 output rows per block: 512/64 = 8, no tail
#define WIN 18               // LDS ring rows (TY + 10)
#define HSTR 65              // col stride >= 64 (!); 5*65=325 ≡ 5 (mod 32) -> 2-way free
#define IMW 512
#define IMH 512
#define NPLANES 96           // 32 * 3
#define NBX (IMW / TX)       // 8
#define NBY (IMH / BYR)      // 8 (pow2: bid decompose by shifts)
#define NBLOCKS (NBX * NBY * NPLANES)  // 6144

// Gaussian(sigma=1.5, ws=11), double-computed, fp32-rounded.
#define GW0 0.00102838f
#define GW1 0.00759877f
#define GW2 0.03600077f
#define GW3 0.10936069f
#define GW4 0.21300553f
#define GW5 0.26601172f

__device__ __forceinline__ void pkfma(v2f& acc, v2f a, v2f b) {
  asm("v_pk_fma_f32 %0, %1, %2, %0" : "+v"(acc) : "v"(a), "v"(b));
}
__device__ __forceinline__ v2f pkmul(v2f a, v2f b) {
  v2f d;
  asm("v_pk_mul_f32 %0, %1, %2" : "=v"(d) : "v"(a), "v"(b));
  return d;
}

// Raw global window for one h-blur row-run: 24 cols of gen + ref.
struct Raw {
  float4 g[6];
  float4 r[6];
};

// Issue global loads for `nrows` rows starting at image row gy0.
// Thread t (t < nrows*8): row t>>3, 8-col output run starting (t&7)*8.
__device__ __forceinline__ void hload(
    const float* __restrict__ gp, const float* __restrict__ rp,
    int x0, bool fast, int nrows, int gy0, int tid, Raw& L) {
  if (tid >= nrows * 8) return;
  const int r = tid >> 3;
  const int xs = (tid & 7) * 8;
  const int gy = gy0 + r;
  const int xbase = x0 + xs - 8;  // window cols [xbase, xbase+24)
  const float* grow = gp + (size_t)gy * IMW;
  const float* rrow = rp + (size_t)gy * IMW;
  if (fast) {
#pragma unroll
    for (int k = 0; k < 6; ++k) {
      L.g[k] = *(const float4*)(grow + xbase + 4 * k);
      L.r[k] = *(const float4*)(rrow + xbase + 4 * k);
    }
  } else {
    const bool rowok = (gy >= 0) & (gy < IMH);
#pragma unroll
    for (int k = 0; k < 6; ++k) {
      const int c = xbase + 4 * k;
      const bool ok = rowok && (c >= 0) && (c < IMW);
      float4 g4 = make_float4(-1.f, -1.f, -1.f, -1.f);
      float4 r4 = g4;  // transform maps -1 -> 0 (matches zero padding)
      if (ok) {
        g4 = *(const float4*)(grow + c);
        r4 = *(const float4*)(rrow + c);
      }
      L.g[k] = g4;
      L.r[k] = r4;
    }
  }
}

// Horizontal 11-tap blur from prefetched registers -> LDS ring slots
// slot0+r (r = tid>>3, slot0 wave-uniform runtime). Layout [slot][5][HSTR].
__device__ __forceinline__ void hcompute(
    const Raw& L, float* __restrict__ sq, int nrows, int slot0, int tid) {
  if (tid >= nrows * 8) return;
  const float GW[11] = {GW0, GW1, GW2, GW3, GW4, GW5,
                        GW4, GW3, GW2, GW1, GW0};
  const int r = tid >> 3;
  const int xs = (tid & 7) * 8;
  int slot = slot0 + r;
  if (slot >= WIN) slot -= WIN;  // slot0<=16, r<=17 -> one subtract suffices

  v2f P[24];  // (g, r) transformed, packed per column
#pragma unroll
  for (int k = 0; k < 6; ++k) {
    const float4 g4 = L.g[k];
    const float4 r4 = L.r[k];
    P[4 * k + 0] = (v2f){fmaf(0.5f, g4.x, 0.5f), fmaf(0.5f, r4.x, 0.5f)};
    P[4 * k + 1] = (v2f){fmaf(0.5f, g4.y, 0.5f), fmaf(0.5f, r4.y, 0.5f)};
    P[4 * k + 2] = (v2f){fmaf(0.5f, g4.z, 0.5f), fmaf(0.5f, r4.z, 0.5f)};
    P[4 * k + 3] = (v2f){fmaf(0.5f, g4.w, 0.5f), fmaf(0.5f, r4.w, 0.5f)};
  }

  v2f accP[8], accQ[8];
  float accS[8];
#pragma unroll
  for (int o = 0; o < 8; ++o) {
    accP[o] = (v2f){0.f, 0.f};
    accQ[o] = (v2f){0.f, 0.f};
    accS[o] = 0.f;
  }

#pragma unroll
  for (int p = 0; p < 18; ++p) {  // window position; col value = P[p+3]
    const v2f pv = P[p + 3];
    const v2f qv = pkmul(pv, pv);
    const float sv = pv.x * pv.y;
    const int olo = (p - 10 < 0) ? 0 : p - 10;
    const int ohi = (p < 7) ? p : 7;
#pragma unroll
    for (int o = olo; o <= ohi; ++o) {
      const float wt = GW[p - o];
      const v2f wv = (v2f){wt, wt};
      pkfma(accP[o], wv, pv);
      pkfma(accQ[o], wv, qv);
      accS[o] = fmaf(wt, sv, accS[o]);
    }
  }

  // P.x/P.y (Q.x/Q.y) are 65 dwords apart -> phase-2 ds_read2_b32 pairs.
  // Store banks: (5r + 8s + o) mod 32 -> exact 2-way per instr (free, m136).
  float* dst = sq + slot * (5 * HSTR) + xs;
#pragma unroll
  for (int o = 0; o < 8; ++o) dst[0 * HSTR + o] = accP[o].x;
#pragma unroll
  for (int o = 0; o < 8; ++o) dst[1 * HSTR + o] = accP[o].y;
#pragma unroll
  for (int o = 0; o < 8; ++o) dst[2 * HSTR + o] = accQ[o].x;
#pragma unroll
  for (int o = 0; o < 8; ++o) dst[3 * HSTR + o] = accQ[o].y;
#pragma unroll
  for (int o = 0; o < 8; ++o) dst[4 * HSTR + o] = accS[o];
}

// Vertical 11-tap blur + SSIM for 2 output rows. wb runtime wave-uniform,
// r0 wave-uniform. All output rows in-range (BYR divides IMH): no y-mask.
__device__ __forceinline__ float phase2(
    const float* __restrict__ sq, int wb, int col, int r0) {
  const float GW[11] = {GW0, GW1, GW2, GW3, GW4, GW5,
                        GW4, GW3, GW2, GW1, GW0};
  v2f hp[12], hq[12];
  float hs[12];
#pragma unroll
  for (int i = 0; i < 12; ++i) {
    int slot = wb + r0 + i;                  // <= 16+6+11 = 33
    if (slot >= WIN) slot -= WIN;            // one subtract suffices
    const float* rowp = sq + slot * (5 * HSTR) + col;
    hp[i] = (v2f){rowp[0 * HSTR], rowp[1 * HSTR]};  // ds_read2_b32 (0,65)
    hq[i] = (v2f){rowp[2 * HSTR], rowp[3 * HSTR]};  // ds_read2_b32 (130,195)
    hs[i] = rowp[4 * HSTR];                         // ds_read_b32 offset 1040B
  }

  const float C1 = 6.5025f, C2 = 58.5225f;
  float lsum = 0.f;
#pragma unroll
  for (int o = 0; o < 2; ++o) {
    v2f mu = (v2f){0.f, 0.f};
    v2f ee = (v2f){0.f, 0.f};
    float e12 = 0.f;
#pragma unroll
    for (int t = 0; t < 11; ++t) {
      const float wt = GW[t];
      const v2f wv = (v2f){wt, wt};
      pkfma(mu, wv, hp[o + t]);
      pkfma(ee, wv, hq[o + t]);
      e12 = fmaf(wt, hs[o + t], e12);
    }
    const float mu1 = mu.x, mu2 = mu.y, e1 = ee.x, e2 = ee.y;
    const float m12 = mu1 * mu2;
    const float m1s = mu1 * mu1;
    const float m2s = mu2 * mu2;
    const float num = (2.f * m12 + C1) * (2.f * (e12 - m12) + C2);
    const float den = (m1s + m2s + C1) * ((e1 - m1s) + (e2 - m2s) + C2);
    lsum += __fdividef(num, den);
  }
  return lsum;
}

__global__ __launch_bounds__(256, 6) void ssim_main(
    const float* __restrict__ gen, const float* __restrict__ ref,
    double* __restrict__ partial) {
  // 8-chunk block: 64 output rows from an 18-row LDS ring (23,400 B ->
  // 6 blocks/CU = 24 waves/CU). Phase-1 rows per block: 18 + 7*8 = 74 for
  // 64 outputs (redundancy 1.156). Ring invariant: winbase_c = 8c mod 18,
  // and chunk c+1's new rows land exactly at slot base = winbase_c.
  __shared__ float s_q[WIN][5][HSTR];
  float* const sq = &s_q[0][0][0];

  const int tid = threadIdx.x;
  const int bid = blockIdx.x;
  const int bx = bid & (NBX - 1);
  const int rem = bid >> 3;
  const int by = rem & (NBY - 1);
  const int plane = rem >> 3;
  const int x0 = bx * TX;
  const int Y0 = by * BYR;
  const float* gp = gen + (size_t)plane * (IMW * IMH);
  const float* rp = ref + (size_t)plane * (IMW * IMH);
  const bool ix = (bx >= 1) & (bx <= NBX - 2);

  const int col = tid & 63;
  // wave-uniform: keep ring addressing on the SALU
  const int r0 = __builtin_amdgcn_readfirstlane((tid >> 6) * 2);

  // Prologue: chunk 0 = h-rows [Y0-5, Y0+13) -> slots 0..17 (144 threads);
  // chunk 1's rows [Y0+13, Y0+21) preloaded into B (64 threads).
  Raw A, B;
  hload(gp, rp, x0, ix & (by > 0), WIN, Y0 - 5, tid, A);
  hcompute(A, sq, WIN, 0, tid);
  hload(gp, rp, x0, ix, TY, Y0 + 13, tid, B);
  __syncthreads();

  double acc = 0.0;
  int wb = 0;  // winbase: 0,8,16,6,14,4,12,2
#pragma unroll 2
  for (int c = 0; c < MY - 1; ++c) {
    acc += (double)phase2(sq, wb, col, r0);
    __syncthreads();  // reads done -> slots wb..wb+7 may be overwritten
    // Compute chunk c+1 (odd chunks live in B, even in A) into slots wb..
    if (c & 1) hcompute(A, sq, TY, wb, tid);
    else       hcompute(B, sq, TY, wb, tid);
    // Load chunk c+2 (rows [Y0+21+8c, +8)) into the buffer just consumed.
    if (c < MY - 2) {
      const int gy0 = Y0 + 21 + 8 * c;
      const bool f = ix && (gy0 + TY <= IMH);
      if (c & 1) hload(gp, rp, x0, f, TY, gy0, tid, B);
      else       hload(gp, rp, x0, f, TY, gy0, tid, A);
    }
    __syncthreads();  // ring writes visible before next phase-2
    wb += TY;
    if (wb >= WIN) wb -= WIN;
  }
  acc += (double)phase2(sq, wb, col, r0);  // chunk 7, wb = 2

  // Block reduction -> one deterministic double partial per block.
  // Ring is dead now: reuse its LDS for the 4 per-wave partials.
#pragma unroll
  for (int off = 32; off > 0; off >>= 1) acc += __shfl_down(acc, off, 64);
  __syncthreads();  // last phase-2 reads done before reuse
  double* swsum = (double*)sq;
  if ((tid & 63) == 0) swsum[tid >> 6] = acc;
  __syncthreads();
  if (tid == 0) partial[bid] = swsum[0] + swsum[1] + swsum[2] + swsum[3];
}

__global__ void ssim_reduce(const double* __restrict__ partial,
                            float* __restrict__ out) {
  const int tid = threadIdx.x;
  double s = 0.0;
  // 6144 = 24 * 256 partials, fixed-order per thread (deterministic).
  for (int i = tid; i < NBLOCKS; i += 256) s += partial[i];
#pragma unroll
  for (int off = 32; off > 0; off >>= 1) s += __shfl_down(s, off, 64);
  __shared__ double sd[4];
  if ((tid & 63) == 0) sd[tid >> 6] = s;
  __syncthreads();
  if (tid == 0) {
    const double npix = (double)NPLANES * (double)IMW * (double)IMH;
    out[0] = (float)(1.0 - (sd[0] + sd[1] + sd[2] + sd[3]) / npix);
  }
}

extern "C" void kernel_launch(void* const* d_in, const int* in_sizes, int n_in,
                              void* d_out, int out_size, void* d_ws, size_t ws_size,
                              hipStream_t stream) {
  (void)in_sizes; (void)n_in; (void)out_size; (void)ws_size;
  const float* gen = (const float*)d_in[0];
  const float* ref = (const float*)d_in[1];
  double* partial = (double*)d_ws;  // NBLOCKS doubles; every slot written each call
  ssim_main<<<NBLOCKS, 256, 0, stream>>>(gen, ref, partial);
  ssim_reduce<<<1, 256, 0, stream>>>(partial, (float*)d_out);
}

// Round 5
// 605.300 us; speedup vs baseline: 1.7258x; 1.7258x over previous
//
#include <hip/hip_runtime.h>

typedef float v2f __attribute__((ext_vector_type(2)));

#define TX 64
#define TY 8                 // output rows per chunk
#define MY 8                 // chunks per block
#define BYR (TY * MY)        // 64 output rows per block: 512/64 = 8, no tail
#define WIN 18               // LDS ring rows (TY + 10)
#define HSTR 65              // col stride >= 64 (!); banks (5r+8s) mod 32 -> 2-way free
#define IMW 512
#define IMH 512
#define NPLANES 96           // 32 * 3
#define NBX (IMW / TX)       // 8
#define NBY (IMH / BYR)      // 8 (pow2: bid decompose by shifts)
#define NBLOCKS (NBX * NBY * NPLANES)  // 6144

// Gaussian(sigma=1.5, ws=11), double-computed, fp32-rounded.
#define GW0 0.00102838f
#define GW1 0.00759877f
#define GW2 0.03600077f
#define GW3 0.10936069f
#define GW4 0.21300553f
#define GW5 0.26601172f

__device__ __forceinline__ void pkfma(v2f& acc, v2f a, v2f b) {
  asm("v_pk_fma_f32 %0, %1, %2, %0" : "+v"(acc) : "v"(a), "v"(b));
}
__device__ __forceinline__ v2f pkmul(v2f a, v2f b) {
  v2f d;
  asm("v_pk_mul_f32 %0, %1, %2" : "=v"(d) : "v"(a), "v"(b));
  return d;
}

// Raw global window for one h-blur row-run: 24 cols of gen + ref.
// ONE buffer in flight (48 VGPRs). Round-4's A/B pair (96 VGPRs) +
// launch_bounds(256,6) forced a spill-everything allocation (VGPR=40,
// WRITE_SIZE 2.15 GB of scratch thrash). Budget: total live <= 64 VGPR.
struct Raw {
  float4 g[6];
  float4 r[6];
};

// Issue global loads for `nrows` rows starting at image row gy0.
// Thread t (t < nrows*8): row t>>3, 8-col output run starting (t&7)*8.
__device__ __forceinline__ void hload(
    const float* __restrict__ gp, const float* __restrict__ rp,
    int x0, bool fast, int nrows, int gy0, int tid, Raw& L) {
  if (tid >= nrows * 8) return;
  const int r = tid >> 3;
  const int xs = (tid & 7) * 8;
  const int gy = gy0 + r;
  const int xbase = x0 + xs - 8;  // window cols [xbase, xbase+24)
  const float* grow = gp + (size_t)gy * IMW;
  const float* rrow = rp + (size_t)gy * IMW;
  if (fast) {
#pragma unroll
    for (int k = 0; k < 6; ++k) {
      L.g[k] = *(const float4*)(grow + xbase + 4 * k);
      L.r[k] = *(const float4*)(rrow + xbase + 4 * k);
    }
  } else {
    const bool rowok = (gy >= 0) & (gy < IMH);
#pragma unroll
    for (int k = 0; k < 6; ++k) {
      const int c = xbase + 4 * k;
      const bool ok = rowok && (c >= 0) && (c < IMW);
      float4 g4 = make_float4(-1.f, -1.f, -1.f, -1.f);
      float4 r4 = g4;  // transform maps -1 -> 0 (matches zero padding)
      if (ok) {
        g4 = *(const float4*)(grow + c);
        r4 = *(const float4*)(rrow + c);
      }
      L.g[k] = g4;
      L.r[k] = r4;
    }
  }
}

// Horizontal 11-tap blur from prefetched registers -> LDS ring slots
// slot0+r (r = tid>>3, slot0 compile-time after unroll). Layout [slot][5][HSTR].
__device__ __forceinline__ void hcompute(
    const Raw& L, float* __restrict__ sq, int nrows, int slot0, int tid) {
  if (tid >= nrows * 8) return;
  const float GW[11] = {GW0, GW1, GW2, GW3, GW4, GW5,
                        GW4, GW3, GW2, GW1, GW0};
  const int r = tid >> 3;
  const int xs = (tid & 7) * 8;
  int slot = slot0 + r;
  if (slot >= WIN) slot -= WIN;  // slot0<=16, r<=17 -> one subtract suffices

  v2f P[24];  // (g, r) transformed, packed per column
#pragma unroll
  for (int k = 0; k < 6; ++k) {
    const float4 g4 = L.g[k];
    const float4 r4 = L.r[k];
    P[4 * k + 0] = (v2f){fmaf(0.5f, g4.x, 0.5f), fmaf(0.5f, r4.x, 0.5f)};
    P[4 * k + 1] = (v2f){fmaf(0.5f, g4.y, 0.5f), fmaf(0.5f, r4.y, 0.5f)};
    P[4 * k + 2] = (v2f){fmaf(0.5f, g4.z, 0.5f), fmaf(0.5f, r4.z, 0.5f)};
    P[4 * k + 3] = (v2f){fmaf(0.5f, g4.w, 0.5f), fmaf(0.5f, r4.w, 0.5f)};
  }

  v2f accP[8], accQ[8];
  float accS[8];
#pragma unroll
  for (int o = 0; o < 8; ++o) {
    accP[o] = (v2f){0.f, 0.f};
    accQ[o] = (v2f){0.f, 0.f};
    accS[o] = 0.f;
  }

#pragma unroll
  for (int p = 0; p < 18; ++p) {  // window position; col value = P[p+3]
    const v2f pv = P[p + 3];
    const v2f qv = pkmul(pv, pv);
    const float sv = pv.x * pv.y;
    const int olo = (p - 10 < 0) ? 0 : p - 10;
    const int ohi = (p < 7) ? p : 7;
#pragma unroll
    for (int o = olo; o <= ohi; ++o) {
      const float wt = GW[p - o];
      const v2f wv = (v2f){wt, wt};
      pkfma(accP[o], wv, pv);
      pkfma(accQ[o], wv, qv);
      accS[o] = fmaf(wt, sv, accS[o]);
    }
  }

  // P.x/P.y (Q.x/Q.y) are 65 dwords apart -> phase-2 ds_read2_b32 pairs.
  float* dst = sq + slot * (5 * HSTR) + xs;
#pragma unroll
  for (int o = 0; o < 8; ++o) dst[0 * HSTR + o] = accP[o].x;
#pragma unroll
  for (int o = 0; o < 8; ++o) dst[1 * HSTR + o] = accP[o].y;
#pragma unroll
  for (int o = 0; o < 8; ++o) dst[2 * HSTR + o] = accQ[o].x;
#pragma unroll
  for (int o = 0; o < 8; ++o) dst[3 * HSTR + o] = accQ[o].y;
#pragma unroll
  for (int o = 0; o < 8; ++o) dst[4 * HSTR + o] = accS[o];
}

// Vertical 11-tap blur + SSIM for 2 output rows. wb compile-time after
// unroll, r0 wave-uniform. All output rows in-range: no y-mask.
__device__ __forceinline__ float phase2(
    const float* __restrict__ sq, int wb, int col, int r0) {
  const float GW[11] = {GW0, GW1, GW2, GW3, GW4, GW5,
                        GW4, GW3, GW2, GW1, GW0};
  v2f hp[12], hq[12];
  float hs[12];
#pragma unroll
  for (int i = 0; i < 12; ++i) {
    int slot = wb + r0 + i;                  // <= 16+6+11 = 33
    if (slot >= WIN) slot -= WIN;            // one subtract suffices
    const float* rowp = sq + slot * (5 * HSTR) + col;
    hp[i] = (v2f){rowp[0 * HSTR], rowp[1 * HSTR]};  // ds_read2_b32 (0,65)
    hq[i] = (v2f){rowp[2 * HSTR], rowp[3 * HSTR]};  // ds_read2_b32 (130,195)
    hs[i] = rowp[4 * HSTR];
  }

  const float C1 = 6.5025f, C2 = 58.5225f;
  float lsum = 0.f;
#pragma unroll
  for (int o = 0; o < 2; ++o) {
    v2f mu = (v2f){0.f, 0.f};
    v2f ee = (v2f){0.f, 0.f};
    float e12 = 0.f;
#pragma unroll
    for (int t = 0; t < 11; ++t) {
      const float wt = GW[t];
      const v2f wv = (v2f){wt, wt};
      pkfma(mu, wv, hp[o + t]);
      pkfma(ee, wv, hq[o + t]);
      e12 = fmaf(wt, hs[o + t], e12);
    }
    const float mu1 = mu.x, mu2 = mu.y, e1 = ee.x, e2 = ee.y;
    const float m12 = mu1 * mu2;
    const float m1s = mu1 * mu1;
    const float m2s = mu2 * mu2;
    const float num = (2.f * m12 + C1) * (2.f * (e12 - m12) + C2);
    const float den = (m1s + m2s + C1) * ((e1 - m1s) + (e2 - m2s) + C2);
    lsum += __fdividef(num, den);
  }
  return lsum;
}

__global__ __launch_bounds__(256, 4) void ssim_main(
    const float* __restrict__ gen, const float* __restrict__ ref,
    double* __restrict__ partial) {
  // 8-chunk block: 64 output rows from an 18-row LDS ring (23,400 B).
  // Occupancy plan: VGPR <= 64 (8 waves/SIMD allowed) -> LDS caps at
  // 6 blocks/CU = 24 waves (75%). launch_bounds min-waves stays 4 so the
  // allocator is NOT starved (round-4 lesson: (256,6) => spill disaster).
  // Phase-1 rows per block: 18 + 7*8 = 74 for 64 outputs (redundancy 1.156).
  __shared__ float s_q[WIN][5][HSTR];
  float* const sq = &s_q[0][0][0];

  const int tid = threadIdx.x;
  const int bid = blockIdx.x;
  const int bx = bid & (NBX - 1);
  const int rem = bid >> 3;
  const int by = rem & (NBY - 1);
  const int plane = rem >> 3;
  const int x0 = bx * TX;
  const int Y0 = by * BYR;
  const float* gp = gen + (size_t)plane * (IMW * IMH);
  const float* rp = ref + (size_t)plane * (IMW * IMH);
  const bool ix = (bx >= 1) & (bx <= NBX - 2);

  const int col = tid & 63;
  // wave-uniform: keep ring addressing on the SALU
  const int r0 = __builtin_amdgcn_readfirstlane((tid >> 6) * 2);

  // Prologue: chunk 0 = h-rows [Y0-5, Y0+13) -> slots 0..17 (144 threads);
  // chunk 1's rows [Y0+13, Y0+21) preloaded into A (64 threads, in flight).
  Raw A;
  hload(gp, rp, x0, ix & (by > 0), WIN, Y0 - 5, tid, A);
  hcompute(A, sq, WIN, 0, tid);
  hload(gp, rp, x0, ix, TY, Y0 + 13, tid, A);
  __syncthreads();

  double acc = 0.0;
  int wb = 0;  // winbase: 0,8,16,6,14,4,12,2 (compile-time after full unroll)
#pragma unroll
  for (int c = 0; c < MY - 1; ++c) {
    acc += (double)phase2(sq, wb, col, r0);
    __syncthreads();  // reads done -> slots wb..wb+7 may be overwritten
    // Chunk c+1's rows (held in A) land at slot base = current wb.
    hcompute(A, sq, TY, wb, tid);
    // Reload A with chunk c+2's rows [Y0+21+8c, +8); consumed next iter
    // after barrier + phase2 (the latency-hiding distance).
    if (c < MY - 2) {
      const int gy0 = Y0 + 21 + 8 * c;
      const bool f = ix && (gy0 + TY <= IMH);
      hload(gp, rp, x0, f, TY, gy0, tid, A);
    }
    __syncthreads();  // ring writes visible before next phase-2
    wb += TY;
    if (wb >= WIN) wb -= WIN;
  }
  acc += (double)phase2(sq, wb, col, r0);  // chunk 7, wb = 2

  // Block reduction -> one deterministic double partial per block.
  // Ring is dead now: reuse its LDS for the 4 per-wave partials.
#pragma unroll
  for (int off = 32; off > 0; off >>= 1) acc += __shfl_down(acc, off, 64);
  __syncthreads();  // last phase-2 reads done before reuse
  double* swsum = (double*)sq;
  if ((tid & 63) == 0) swsum[tid >> 6] = acc;
  __syncthreads();
  if (tid == 0) partial[bid] = swsum[0] + swsum[1] + swsum[2] + swsum[3];
}

__global__ void ssim_reduce(const double* __restrict__ partial,
                            float* __restrict__ out) {
  const int tid = threadIdx.x;
  double s = 0.0;
  // 6144 = 24 * 256 partials, fixed-order per thread (deterministic).
  for (int i = tid; i < NBLOCKS; i += 256) s += partial[i];
#pragma unroll
  for (int off = 32; off > 0; off >>= 1) s += __shfl_down(s, off, 64);
  __shared__ double sd[4];
  if ((tid & 63) == 0) sd[tid >> 6] = s;
  __syncthreads();
  if (tid == 0) {
    const double npix = (double)NPLANES * (double)IMW * (double)IMH;
    out[0] = (float)(1.0 - (sd[0] + sd[1] + sd[2] + sd[3]) / npix);
  }
}

extern "C" void kernel_launch(void* const* d_in, const int* in_sizes, int n_in,
                              void* d_out, int out_size, void* d_ws, size_t ws_size,
                              hipStream_t stream) {
  (void)in_sizes; (void)n_in; (void)out_size; (void)ws_size;
  const float* gen = (const float*)d_in[0];
  const float* ref = (const float*)d_in[1];
  double* partial = (double*)d_ws;  // NBLOCKS doubles; every slot written each call
  ssim_main<<<NBLOCKS, 256, 0, stream>>>(gen, ref, partial);
  ssim_reduce<<<1, 256, 0, stream>>>(partial, (float*)d_out);
}

// Round 6
// 394.227 us; speedup vs baseline: 2.6498x; 1.5354x over previous
//
#include <hip/hip_runtime.h>

typedef float v2f __attribute__((ext_vector_type(2)));

#define TX 64
#define TY 8                 // output rows per chunk
#define MY 8                 // chunks per block
#define BYR (TY * MY)        // 64 output rows per block: 512/64 = 8, no tail
#define WIN 18               // LDS ring rows (TY + 10)
#define HSTR 65              // col stride >= 64; banks (5*slot+col) mod 32 -> 2-way free
#define IMW 512
#define IMH 512
#define NPLANES 96           // 32 * 3
#define NBX (IMW / TX)       // 8
#define NBY (IMH / BYR)      // 8 (pow2: bid decompose by shifts)
#define NBLOCKS (NBX * NBY * NPLANES)  // 6144

// Gaussian(sigma=1.5, ws=11), double-computed, fp32-rounded.
#define GW0 0.00102838f
#define GW1 0.00759877f
#define GW2 0.03600077f
#define GW3 0.10936069f
#define GW4 0.21300553f
#define GW5 0.26601172f

__device__ __forceinline__ void pkfma(v2f& acc, v2f a, v2f b) {
  asm("v_pk_fma_f32 %0, %1, %2, %0" : "+v"(acc) : "v"(a), "v"(b));
}
__device__ __forceinline__ v2f pkmul(v2f a, v2f b) {
  v2f d;
  asm("v_pk_mul_f32 %0, %1, %2" : "=v"(d) : "v"(a), "v"(b));
  return d;
}

// ---- Phase 1: horizontal 11-tap blur, LOAD-AND-COMPUTE (no cross-barrier
// register state -- rounds 4/5 proved prefetch Raws just spill to scratch).
// 16 threads/row x 4 outputs each: window = 14 cols, loaded as 5 aligned
// float4 [xs-8, xs+12). nrows=8 -> 128 threads (2 waves) per chunk.
__device__ __forceinline__ void hblur4(
    const float* __restrict__ gp, const float* __restrict__ rp,
    float* __restrict__ sq, int x0, bool fast, int nrows, int gy0,
    int slot0, int tid) {
  if (tid >= nrows * 16) return;
  const float GW[11] = {GW0, GW1, GW2, GW3, GW4, GW5,
                        GW4, GW3, GW2, GW1, GW0};
  const int r = tid >> 4;
  const int xs = (tid & 15) * 4;
  const int gy = gy0 + r;
  int slot = slot0 + r;
  if (slot >= WIN) slot -= WIN;  // slot0<=16, r<=15 -> one subtract suffices
  const int xbase = x0 + xs - 8;  // loaded cols [xbase, xbase+20)
  const float* grow = gp + (size_t)gy * IMW;
  const float* rrow = rp + (size_t)gy * IMW;

  float ga[20], ra[20];
  if (fast) {
#pragma unroll
    for (int k = 0; k < 5; ++k) {
      const float4 g4 = *(const float4*)(grow + xbase + 4 * k);
      const float4 r4 = *(const float4*)(rrow + xbase + 4 * k);
      ga[4 * k + 0] = g4.x; ga[4 * k + 1] = g4.y;
      ga[4 * k + 2] = g4.z; ga[4 * k + 3] = g4.w;
      ra[4 * k + 0] = r4.x; ra[4 * k + 1] = r4.y;
      ra[4 * k + 2] = r4.z; ra[4 * k + 3] = r4.w;
    }
  } else {
    const bool rowok = (gy >= 0) & (gy < IMH);
#pragma unroll
    for (int k = 0; k < 5; ++k) {
      const int c = xbase + 4 * k;
      const bool ok = rowok && (c >= 0) && (c < IMW);
      float4 g4 = make_float4(-1.f, -1.f, -1.f, -1.f);
      float4 r4 = g4;  // transform maps -1 -> 0 (matches zero padding)
      if (ok) {
        g4 = *(const float4*)(grow + c);
        r4 = *(const float4*)(rrow + c);
      }
      ga[4 * k + 0] = g4.x; ga[4 * k + 1] = g4.y;
      ga[4 * k + 2] = g4.z; ga[4 * k + 3] = g4.w;
      ra[4 * k + 0] = r4.x; ra[4 * k + 1] = r4.y;
      ra[4 * k + 2] = r4.z; ra[4 * k + 3] = r4.w;
    }
  }

  v2f accP[4], accQ[4];
  float accS[4];
#pragma unroll
  for (int o = 0; o < 4; ++o) {
    accP[o] = (v2f){0.f, 0.f};
    accQ[o] = (v2f){0.f, 0.f};
    accS[o] = 0.f;
  }

  // Window position p: input col xs-5+p (index p+3); output o uses p=o..o+10.
  // Indices 0..2 and 17..19 feed nothing -> their transforms DCE away.
#pragma unroll
  for (int p = 0; p < 14; ++p) {
    const int j = p + 3;
    const v2f pv = (v2f){fmaf(0.5f, ga[j], 0.5f), fmaf(0.5f, ra[j], 0.5f)};
    const v2f qv = pkmul(pv, pv);
    const float sv = pv.x * pv.y;
    const int olo = (p - 10 < 0) ? 0 : p - 10;
    const int ohi = (p < 3) ? p : 3;
#pragma unroll
    for (int o = olo; o <= ohi; ++o) {
      const float wt = GW[p - o];
      const v2f wv = (v2f){wt, wt};
      pkfma(accP[o], wv, pv);
      pkfma(accQ[o], wv, qv);
      accS[o] = fmaf(wt, sv, accS[o]);
    }
  }

  // P.x/P.y (Q.x/Q.y) are 65 dwords apart -> phase-2 ds_read2_b32 pairs.
  // Store banks: (5*slot + xs + o) mod 32 over 4 rows x 16 runs -> exact
  // 2-way per instruction (free, m136).
  float* dst = sq + slot * (5 * HSTR) + xs;
#pragma unroll
  for (int o = 0; o < 4; ++o) dst[0 * HSTR + o] = accP[o].x;
#pragma unroll
  for (int o = 0; o < 4; ++o) dst[1 * HSTR + o] = accP[o].y;
#pragma unroll
  for (int o = 0; o < 4; ++o) dst[2 * HSTR + o] = accQ[o].x;
#pragma unroll
  for (int o = 0; o < 4; ++o) dst[3 * HSTR + o] = accQ[o].y;
#pragma unroll
  for (int o = 0; o < 4; ++o) dst[4 * HSTR + o] = accS[o];
}

__device__ __forceinline__ float ssim_px(v2f mu, v2f ee, float e12) {
  const float C1 = 6.5025f, C2 = 58.5225f;
  const float mu1 = mu.x, mu2 = mu.y, e1 = ee.x, e2 = ee.y;
  const float m12 = mu1 * mu2;
  const float m1s = mu1 * mu1;
  const float m2s = mu2 * mu2;
  const float num = (2.f * m12 + C1) * (2.f * (e12 - m12) + C2);
  const float den = (m1s + m2s + C1) * ((e1 - m1s) + (e2 - m2s) + C2);
  return __fdividef(num, den);
}

// ---- Phase 2: vertical 11-tap blur + SSIM for 2 output rows, STREAMING
// (accumulate while reading: peak ~20 VGPRs instead of 60-element arrays).
// wb compile-time after unroll, r0 wave-uniform. No y-mask (BYR | IMH).
__device__ __forceinline__ float phase2(
    const float* __restrict__ sq, int wb, int col, int r0) {
  const float GW[11] = {GW0, GW1, GW2, GW3, GW4, GW5,
                        GW4, GW3, GW2, GW1, GW0};
  v2f mu0 = (v2f){0.f, 0.f}, mu1 = (v2f){0.f, 0.f};
  v2f ee0 = (v2f){0.f, 0.f}, ee1 = (v2f){0.f, 0.f};
  float e0 = 0.f, e1 = 0.f;
#pragma unroll
  for (int i = 0; i < 12; ++i) {
    int slot = wb + r0 + i;        // <= 16+6+11 = 33
    if (slot >= WIN) slot -= WIN;  // one subtract suffices
    const float* rowp = sq + slot * (5 * HSTR) + col;
    const v2f hp = (v2f){rowp[0 * HSTR], rowp[1 * HSTR]};  // ds_read2_b32
    const v2f hq = (v2f){rowp[2 * HSTR], rowp[3 * HSTR]};  // ds_read2_b32
    const float hsv = rowp[4 * HSTR];
    if (i <= 10) {  // row i is tap i of output 0
      const float wt = GW[i];
      const v2f wv = (v2f){wt, wt};
      pkfma(mu0, wv, hp);
      pkfma(ee0, wv, hq);
      e0 = fmaf(wt, hsv, e0);
    }
    if (i >= 1) {   // row i is tap i-1 of output 1
      const float wt = GW[i - 1];
      const v2f wv = (v2f){wt, wt};
      pkfma(mu1, wv, hp);
      pkfma(ee1, wv, hq);
      e1 = fmaf(wt, hsv, e1);
    }
  }
  return ssim_px(mu0, ee0, e0) + ssim_px(mu1, ee1, e1);
}

__global__ __launch_bounds__(256, 4) void ssim_main(
    const float* __restrict__ gen, const float* __restrict__ ref,
    double* __restrict__ partial) {
  // 8-chunk block, 18-row LDS ring (23,400 B -> 6 blocks/CU = 24 waves/CU).
  // NOTHING lives in registers across a barrier except `acc` (1 double):
  // latency hiding is occupancy's job, not the register file's (r4/r5 lesson).
  // Phase-1 rows per block: 18 + 7*8 = 74 for 64 outputs (redundancy 1.156).
  __shared__ float s_q[WIN][5][HSTR];
  float* const sq = &s_q[0][0][0];

  const int tid = threadIdx.x;
  const int bid = blockIdx.x;
  const int bx = bid & (NBX - 1);
  const int rem = bid >> 3;
  const int by = rem & (NBY - 1);
  const int plane = rem >> 3;
  const int x0 = bx * TX;
  const int Y0 = by * BYR;
  const float* gp = gen + (size_t)plane * (IMW * IMH);
  const float* rp = ref + (size_t)plane * (IMW * IMH);
  const bool ix = (bx >= 1) & (bx <= NBX - 2);

  const int col = tid & 63;
  // wave-uniform: keep ring addressing on the SALU
  const int r0 = __builtin_amdgcn_readfirstlane((tid >> 6) * 2);

  // Prologue: 18 h-rows [Y0-5, Y0+13) -> slots 0..17, split 16+2 so the
  // first call uses all 256 threads.
  hblur4(gp, rp, sq, x0, ix & (by > 0), 16, Y0 - 5, 0, tid);
  hblur4(gp, rp, sq, x0, ix, 2, Y0 + 11, 16, tid);
  __syncthreads();

  double acc = 0.0;
  int wb = 0;  // winbase: 0,8,16,6,14,4,12,2 (compile-time after full unroll)
#pragma unroll
  for (int c = 0; c < MY; ++c) {
    acc += (double)phase2(sq, wb, col, r0);
    if (c < MY - 1) {
      __syncthreads();  // all reads done (phase2 reads the whole ring)
      // Chunk c+1's new h-rows [Y0+13+8c, +8) land at slot base = wb.
      const int gy0 = Y0 + 13 + 8 * c;
      hblur4(gp, rp, sq, x0, ix && (gy0 + TY <= IMH), TY, gy0, wb, tid);
      __syncthreads();  // ring writes visible before next phase-2
      wb += TY;
      if (wb >= WIN) wb -= WIN;
    }
  }

  // Block reduction -> one deterministic double partial per block.
  // Ring is dead now: reuse its LDS for the 4 per-wave partials.
#pragma unroll
  for (int off = 32; off > 0; off >>= 1) acc += __shfl_down(acc, off, 64);
  __syncthreads();  // last phase-2 reads done before reuse
  double* swsum = (double*)sq;
  if ((tid & 63) == 0) swsum[tid >> 6] = acc;
  __syncthreads();
  if (tid == 0) partial[bid] = swsum[0] + swsum[1] + swsum[2] + swsum[3];
}

__global__ void ssim_reduce(const double* __restrict__ partial,
                            float* __restrict__ out) {
  const int tid = threadIdx.x;
  double s = 0.0;
  // 6144 = 24 * 256 partials, fixed-order per thread (deterministic).
  for (int i = tid; i < NBLOCKS; i += 256) s += partial[i];
#pragma unroll
  for (int off = 32; off > 0; off >>= 1) s += __shfl_down(s, off, 64);
  __shared__ double sd[4];
  if ((tid & 63) == 0) sd[tid >> 6] = s;
  __syncthreads();
  if (tid == 0) {
    const double npix = (double)NPLANES * (double)IMW * (double)IMH;
    out[0] = (float)(1.0 - (sd[0] + sd[1] + sd[2] + sd[3]) / npix);
  }
}

extern "C" void kernel_launch(void* const* d_in, const int* in_sizes, int n_in,
                              void* d_out, int out_size, void* d_ws, size_t ws_size,
                              hipStream_t stream) {
  (void)in_sizes; (void)n_in; (void)out_size; (void)ws_size;
  const float* gen = (const float*)d_in[0];
  const float* ref = (const float*)d_in[1];
  double* partial = (double*)d_ws;  // NBLOCKS doubles; every slot written each call
  ssim_main<<<NBLOCKS, 256, 0, stream>>>(gen, ref, partial);
  ssim_reduce<<<1, 256, 0, stream>>>(partial, (float*)d_out);
}

// Round 7
// 357.015 us; speedup vs baseline: 2.9260x; 1.1042x over previous
//
#include <hip/hip_runtime.h>

typedef float v2f __attribute__((ext_vector_type(2)));

#define TX 64
#define TY 8                 // output rows per chunk
#define MY 8                 // chunks per block
#define BYR (TY * MY)        // 64 output rows per block: 512/64 = 8, no tail
#define WIN 18               // LDS ring rows (TY + 10)
#define HSTR 65              // col stride >= 64; banks (5*slot+col) mod 32 -> 2-way free
#define IMW 512
#define IMH 512
#define NPLANES 96           // 32 * 3
#define NBX (IMW / TX)       // 8
#define NBY (IMH / BYR)      // 8 (pow2: bid decompose by shifts)
#define NBLOCKS (NBX * NBY * NPLANES)  // 6144

// Gaussian(sigma=1.5, ws=11), double-computed, fp32-rounded.
#define GW0 0.00102838f
#define GW1 0.00759877f
#define GW2 0.03600077f
#define GW3 0.10936069f
#define GW4 0.21300553f
#define GW5 0.26601172f

__device__ __forceinline__ void pkfma(v2f& acc, v2f a, v2f b) {
  asm("v_pk_fma_f32 %0, %1, %2, %0" : "+v"(acc) : "v"(a), "v"(b));
}
__device__ __forceinline__ v2f pkmul(v2f a, v2f b) {
  v2f d;
  asm("v_pk_mul_f32 %0, %1, %2" : "=v"(d) : "v"(a), "v"(b));
  return d;
}

// ---- Phase 1: horizontal 11-tap blur, load-and-compute, NO per-thread
// scalar arrays (rounds 4/5/6 lesson: Raw structs / float ga[20] aggregates
// get demoted to scratch -> 181-674 MB of WRITE_SIZE thrash). float4 loads
// feed v2f P[14] directly with compile-time indices (round-2's proven
// no-spill pattern). 16 threads/row x 4 outputs; window cols xs-5..xs+8
// live in P[0..13]; loads cover [xs-8, xs+12) as 5 aligned float4.
__device__ __forceinline__ void hblur4(
    const float* __restrict__ gp, const float* __restrict__ rp,
    float* __restrict__ sq, int x0, bool fast, int nrows, int gy0,
    int slot0, int tid) {
  if (tid >= nrows * 16) return;
  const float GW[11] = {GW0, GW1, GW2, GW3, GW4, GW5,
                        GW4, GW3, GW2, GW1, GW0};
  const int r = tid >> 4;
  const int xs = (tid & 15) * 4;
  const int gy = gy0 + r;
  int slot = slot0 + r;
  if (slot >= WIN) slot -= WIN;  // slot0<=16, r<=15 -> one subtract suffices
  const int xbase = x0 + xs - 8;  // loaded cols [xbase, xbase+20)
  const float* grow = gp + (size_t)gy * IMW;
  const float* rrow = rp + (size_t)gy * IMW;

  v2f P[14];  // transformed (g,r), window position p <-> loaded col index p+3
#define PUT1(idx, gc, rc)                                                    \
  do {                                                                       \
    if ((idx) >= 3 && (idx) <= 16)                                           \
      P[(idx) - 3] = (v2f){fmaf(0.5f, (gc), 0.5f), fmaf(0.5f, (rc), 0.5f)};  \
  } while (0)
  if (fast) {
#pragma unroll
    for (int k = 0; k < 5; ++k) {
      const float4 g4 = *(const float4*)(grow + xbase + 4 * k);
      const float4 r4 = *(const float4*)(rrow + xbase + 4 * k);
      PUT1(4 * k + 0, g4.x, r4.x);
      PUT1(4 * k + 1, g4.y, r4.y);
      PUT1(4 * k + 2, g4.z, r4.z);
      PUT1(4 * k + 3, g4.w, r4.w);
    }
  } else {
    const bool rowok = (gy >= 0) & (gy < IMH);
#pragma unroll
    for (int k = 0; k < 5; ++k) {
      const int c = xbase + 4 * k;
      const bool ok = rowok && (c >= 0) && (c < IMW);
      float4 g4 = make_float4(-1.f, -1.f, -1.f, -1.f);
      float4 r4 = g4;  // transform maps -1 -> 0 (matches zero padding)
      if (ok) {
        g4 = *(const float4*)(grow + c);
        r4 = *(const float4*)(rrow + c);
      }
      PUT1(4 * k + 0, g4.x, r4.x);
      PUT1(4 * k + 1, g4.y, r4.y);
      PUT1(4 * k + 2, g4.z, r4.z);
      PUT1(4 * k + 3, g4.w, r4.w);
    }
  }
#undef PUT1

  v2f accP[4], accQ[4];
  float accS[4];
#pragma unroll
  for (int o = 0; o < 4; ++o) {
    accP[o] = (v2f){0.f, 0.f};
    accQ[o] = (v2f){0.f, 0.f};
    accS[o] = 0.f;
  }

  // Output o (col xs+o) uses window positions p = o..o+10.
#pragma unroll
  for (int p = 0; p < 14; ++p) {
    const v2f pv = P[p];
    const v2f qv = pkmul(pv, pv);
    const float sv = pv.x * pv.y;
    const int olo = (p - 10 < 0) ? 0 : p - 10;
    const int ohi = (p < 3) ? p : 3;
#pragma unroll
    for (int o = olo; o <= ohi; ++o) {
      const float wt = GW[p - o];
      const v2f wv = (v2f){wt, wt};
      pkfma(accP[o], wv, pv);
      pkfma(accQ[o], wv, qv);
      accS[o] = fmaf(wt, sv, accS[o]);
    }
  }

  // P.x/P.y (Q.x/Q.y) are 65 dwords apart -> phase-2 ds_read2_b32 pairs.
  // Store banks: (5*slot + xs + o) mod 32 over a wave (4 rows x 16 runs)
  // -> exactly 2 lanes/bank per instruction (free, m136).
  float* dst = sq + slot * (5 * HSTR) + xs;
#pragma unroll
  for (int o = 0; o < 4; ++o) dst[0 * HSTR + o] = accP[o].x;
#pragma unroll
  for (int o = 0; o < 4; ++o) dst[1 * HSTR + o] = accP[o].y;
#pragma unroll
  for (int o = 0; o < 4; ++o) dst[2 * HSTR + o] = accQ[o].x;
#pragma unroll
  for (int o = 0; o < 4; ++o) dst[3 * HSTR + o] = accQ[o].y;
#pragma unroll
  for (int o = 0; o < 4; ++o) dst[4 * HSTR + o] = accS[o];
}

__device__ __forceinline__ float ssim_px(v2f mu, v2f ee, float e12) {
  const float C1 = 6.5025f, C2 = 58.5225f;
  const float mu1 = mu.x, mu2 = mu.y, e1 = ee.x, e2 = ee.y;
  const float m12 = mu1 * mu2;
  const float m1s = mu1 * mu1;
  const float m2s = mu2 * mu2;
  const float num = (2.f * m12 + C1) * (2.f * (e12 - m12) + C2);
  const float den = (m1s + m2s + C1) * ((e1 - m1s) + (e2 - m2s) + C2);
  return __fdividef(num, den);
}

// ---- Phase 2: vertical 11-tap blur + SSIM for 2 output rows, streaming
// accumulate (no row arrays; live set ~20 VGPR). wb/r0 wave-uniform.
// All output rows in-range (BYR | IMH): no y-mask.
__device__ __forceinline__ float phase2(
    const float* __restrict__ sq, int wb, int col, int r0) {
  const float GW[11] = {GW0, GW1, GW2, GW3, GW4, GW5,
                        GW4, GW3, GW2, GW1, GW0};
  v2f mu0 = (v2f){0.f, 0.f}, mu1 = (v2f){0.f, 0.f};
  v2f ee0 = (v2f){0.f, 0.f}, ee1 = (v2f){0.f, 0.f};
  float e0 = 0.f, e1 = 0.f;
#pragma unroll
  for (int i = 0; i < 12; ++i) {
    int slot = wb + r0 + i;        // <= 16+6+11 = 33
    if (slot >= WIN) slot -= WIN;  // one subtract suffices
    const float* rowp = sq + slot * (5 * HSTR) + col;
    const v2f hp = (v2f){rowp[0 * HSTR], rowp[1 * HSTR]};  // ds_read2_b32
    const v2f hq = (v2f){rowp[2 * HSTR], rowp[3 * HSTR]};  // ds_read2_b32
    const float hsv = rowp[4 * HSTR];
    if (i <= 10) {  // row i is tap i of output 0
      const float wt = GW[i];
      const v2f wv = (v2f){wt, wt};
      pkfma(mu0, wv, hp);
      pkfma(ee0, wv, hq);
      e0 = fmaf(wt, hsv, e0);
    }
    if (i >= 1) {   // row i is tap i-1 of output 1
      const float wt = GW[i - 1];
      const v2f wv = (v2f){wt, wt};
      pkfma(mu1, wv, hp);
      pkfma(ee1, wv, hq);
      e1 = fmaf(wt, hsv, e1);
    }
  }
  return ssim_px(mu0, ee0, e0) + ssim_px(mu1, ee1, e1);
}

__global__ __launch_bounds__(256, 4) void ssim_main(
    const float* __restrict__ gen, const float* __restrict__ ref,
    double* __restrict__ partial) {
  // 8-chunk block, 18-row LDS ring (23,400 B -> 6 blocks/CU = 24 waves/CU).
  // Nothing lives in registers across a barrier except `acc` (1 double).
  // Chunk loop deliberately NOT unrolled: 8x-inlined bodies give the
  // scheduler a ~3000-instr scope and it buys ILP with spills (round 6).
  __shared__ float s_q[WIN][5][HSTR];
  float* const sq = &s_q[0][0][0];

  const int tid = threadIdx.x;
  const int bid = blockIdx.x;
  const int bx = bid & (NBX - 1);
  const int rem = bid >> 3;
  const int by = rem & (NBY - 1);
  const int plane = rem >> 3;
  const int x0 = bx * TX;
  const int Y0 = by * BYR;
  const float* gp = gen + (size_t)plane * (IMW * IMH);
  const float* rp = ref + (size_t)plane * (IMW * IMH);
  const bool ix = (bx >= 1) & (bx <= NBX - 2);

  const int col = tid & 63;
  // wave-uniform: keep ring addressing on the SALU
  const int r0 = __builtin_amdgcn_readfirstlane((tid >> 6) * 2);

  // Prologue: 18 h-rows [Y0-5, Y0+13) -> slots 0..17, split 16+2 so the
  // first call uses all 256 threads.
  hblur4(gp, rp, sq, x0, ix & (by > 0), 16, Y0 - 5, 0, tid);
  hblur4(gp, rp, sq, x0, ix, 2, Y0 + 11, 16, tid);
  __syncthreads();

  double acc = 0.0;
  int wb = 0;  // winbase: (8c) mod 18 = 0,8,16,6,14,4,12,2
#pragma unroll 1
  for (int c = 0; c < MY; ++c) {
    acc += (double)phase2(sq, wb, col, r0);
    if (c < MY - 1) {
      __syncthreads();  // all reads done (phase2 reads the whole ring)
      // Chunk c+1's new h-rows [Y0+13+8c, +8) land at slot base = wb.
      const int gy0 = Y0 + 13 + TY * c;
      hblur4(gp, rp, sq, x0, ix && (gy0 + TY <= IMH), TY, gy0, wb, tid);
      __syncthreads();  // ring writes visible before next phase-2
      wb += TY;
      if (wb >= WIN) wb -= WIN;
    }
  }

  // Block reduction -> one deterministic double partial per block.
  // Ring is dead now: reuse its LDS for the 4 per-wave partials.
#pragma unroll
  for (int off = 32; off > 0; off >>= 1) acc += __shfl_down(acc, off, 64);
  __syncthreads();  // last phase-2 reads done before reuse
  double* swsum = (double*)sq;
  if ((tid & 63) == 0) swsum[tid >> 6] = acc;
  __syncthreads();
  if (tid == 0) partial[bid] = swsum[0] + swsum[1] + swsum[2] + swsum[3];
}

__global__ void ssim_reduce(const double* __restrict__ partial,
                            float* __restrict__ out) {
  const int tid = threadIdx.x;
  double s = 0.0;
  // 6144 = 24 * 256 partials, fixed-order per thread (deterministic).
  for (int i = tid; i < NBLOCKS; i += 256) s += partial[i];
#pragma unroll
  for (int off = 32; off > 0; off >>= 1) s += __shfl_down(s, off, 64);
  __shared__ double sd[4];
  if ((tid & 63) == 0) sd[tid >> 6] = s;
  __syncthreads();
  if (tid == 0) {
    const double npix = (double)NPLANES * (double)IMW * (double)IMH;
    out[0] = (float)(1.0 - (sd[0] + sd[1] + sd[2] + sd[3]) / npix);
  }
}

extern "C" void kernel_launch(void* const* d_in, const int* in_sizes, int n_in,
                              void* d_out, int out_size, void* d_ws, size_t ws_size,
                              hipStream_t stream) {
  (void)in_sizes; (void)n_in; (void)out_size; (void)ws_size;
  const float* gen = (const float*)d_in[0];
  const float* ref = (const float*)d_in[1];
  double* partial = (double*)d_ws;  // NBLOCKS doubles; every slot written each call
  ssim_main<<<NBLOCKS, 256, 0, stream>>>(gen, ref, partial);
  ssim_reduce<<<1, 256, 0, stream>>>(partial, (float*)d_out);
}

// Round 8
// 325.788 us; speedup vs baseline: 3.2064x; 1.0958x over previous
//
#include <hip/hip_runtime.h>

typedef float v2f __attribute__((ext_vector_type(2)));

#define TX 64
#define TY 8                 // output rows per chunk
#define MY 8                 // chunks per block
#define BYR (TY * MY)        // 64 output rows per block: 512/64 = 8, no tail
#define WIN 26               // LDS ring: 18-row read window + 8-row write region
#define HSTR 65              // col stride >= 64; phase-2 reads stride-1 -> 2-way free
#define IMW 512
#define IMH 512
#define NPLANES 96           // 32 * 3
#define NBX (IMW / TX)       // 8
#define NBY (IMH / BYR)      // 8 (pow2: bid decompose by shifts)
#define NBLOCKS (NBX * NBY * NPLANES)  // 6144

// Gaussian(sigma=1.5, ws=11), double-computed, fp32-rounded.
#define GW0 0.00102838f
#define GW1 0.00759877f
#define GW2 0.03600077f
#define GW3 0.10936069f
#define GW4 0.21300553f
#define GW5 0.26601172f

__device__ __forceinline__ void pkfma(v2f& acc, v2f a, v2f b) {
  asm("v_pk_fma_f32 %0, %1, %2, %0" : "+v"(acc) : "v"(a), "v"(b));
}
__device__ __forceinline__ v2f pkmul(v2f a, v2f b) {
  v2f d;
  asm("v_pk_mul_f32 %0, %1, %2" : "=v"(d) : "v"(a), "v"(b));
  return d;
}

// ---- Phase 1 (producer): horizontal 11-tap blur, load-and-compute, NO
// per-thread aggregates (r4/r5/r6 lesson: structs/arrays -> scratch thrash;
// float4 -> v2f P[14] with compile-time indices is the proven no-spill form).
// 16 threads/row x 4 outputs; window cols xs-5..xs+8 in P[0..13]; loads
// cover [xs-8, xs+12) as 5 aligned float4.
__device__ __forceinline__ void hblur4(
    const float* __restrict__ gp, const float* __restrict__ rp,
    float* __restrict__ sq, int x0, bool fast, int nrows, int gy0,
    int slot0, int tid) {
  if (tid >= nrows * 16) return;
  const float GW[11] = {GW0, GW1, GW2, GW3, GW4, GW5,
                        GW4, GW3, GW2, GW1, GW0};
  const int r = tid >> 4;
  const int xs = (tid & 15) * 4;
  const int gy = gy0 + r;
  int slot = slot0 + r;
  if (slot >= WIN) slot -= WIN;  // slot0<=24, r<=15 -> one subtract suffices
  const int xbase = x0 + xs - 8;  // loaded cols [xbase, xbase+20)
  const float* grow = gp + (size_t)gy * IMW;
  const float* rrow = rp + (size_t)gy * IMW;

  v2f P[14];  // transformed (g,r); window position p <-> loaded col p+3
#define PUT1(idx, gc, rc)                                                    \
  do {                                                                       \
    if ((idx) >= 3 && (idx) <= 16)                                           \
      P[(idx) - 3] = (v2f){fmaf(0.5f, (gc), 0.5f), fmaf(0.5f, (rc), 0.5f)};  \
  } while (0)
  if (fast) {
#pragma unroll
    for (int k = 0; k < 5; ++k) {
      const float4 g4 = *(const float4*)(grow + xbase + 4 * k);
      const float4 r4 = *(const float4*)(rrow + xbase + 4 * k);
      PUT1(4 * k + 0, g4.x, r4.x);
      PUT1(4 * k + 1, g4.y, r4.y);
      PUT1(4 * k + 2, g4.z, r4.z);
      PUT1(4 * k + 3, g4.w, r4.w);
    }
  } else {
    const bool rowok = (gy >= 0) & (gy < IMH);
#pragma unroll
    for (int k = 0; k < 5; ++k) {
      const int c = xbase + 4 * k;
      const bool ok = rowok && (c >= 0) && (c < IMW);
      float4 g4 = make_float4(-1.f, -1.f, -1.f, -1.f);
      float4 r4 = g4;  // transform maps -1 -> 0 (matches zero padding)
      if (ok) {
        g4 = *(const float4*)(grow + c);
        r4 = *(const float4*)(rrow + c);
      }
      PUT1(4 * k + 0, g4.x, r4.x);
      PUT1(4 * k + 1, g4.y, r4.y);
      PUT1(4 * k + 2, g4.z, r4.z);
      PUT1(4 * k + 3, g4.w, r4.w);
    }
  }
#undef PUT1

  v2f accP[4], accQ[4];
  float accS[4];
#pragma unroll
  for (int o = 0; o < 4; ++o) {
    accP[o] = (v2f){0.f, 0.f};
    accQ[o] = (v2f){0.f, 0.f};
    accS[o] = 0.f;
  }

  // Output o (col xs+o) uses window positions p = o..o+10.
#pragma unroll
  for (int p = 0; p < 14; ++p) {
    const v2f pv = P[p];
    const v2f qv = pkmul(pv, pv);
    const float sv = pv.x * pv.y;
    const int olo = (p - 10 < 0) ? 0 : p - 10;
    const int ohi = (p < 3) ? p : 3;
#pragma unroll
    for (int o = olo; o <= ohi; ++o) {
      const float wt = GW[p - o];
      const v2f wv = (v2f){wt, wt};
      pkfma(accP[o], wv, pv);
      pkfma(accQ[o], wv, qv);
      accS[o] = fmaf(wt, sv, accS[o]);
    }
  }

  // P.x/P.y (Q.x/Q.y) are 65 dwords apart -> consumer ds_read2_b32 pairs.
  // Store banks: (5*slot + xs + o) mod 32 over a wave -> exactly 2
  // lanes/bank per instruction (free, m136).
  float* dst = sq + slot * (5 * HSTR) + xs;
#pragma unroll
  for (int o = 0; o < 4; ++o) dst[0 * HSTR + o] = accP[o].x;
#pragma unroll
  for (int o = 0; o < 4; ++o) dst[1 * HSTR + o] = accP[o].y;
#pragma unroll
  for (int o = 0; o < 4; ++o) dst[2 * HSTR + o] = accQ[o].x;
#pragma unroll
  for (int o = 0; o < 4; ++o) dst[3 * HSTR + o] = accQ[o].y;
#pragma unroll
  for (int o = 0; o < 4; ++o) dst[4 * HSTR + o] = accS[o];
}

__device__ __forceinline__ float ssim_px(v2f mu, v2f ee, float e12) {
  const float C1 = 6.5025f, C2 = 58.5225f;
  const float mu1 = mu.x, mu2 = mu.y, e1 = ee.x, e2 = ee.y;
  const float m12 = mu1 * mu2;
  const float m1s = mu1 * mu1;
  const float m2s = mu2 * mu2;
  const float num = (2.f * m12 + C1) * (2.f * (e12 - m12) + C2);
  const float den = (m1s + m2s + C1) * ((e1 - m1s) + (e2 - m2s) + C2);
  return __fdividef(num, den);
}

// ---- Phase 2 (consumer): vertical 11-tap blur + SSIM for FOUR output rows
// per wave, streaming over 15 ring rows (acc live set: 4x5 = 20 VGPR).
// wb runtime, r0 wave-uniform {0,4}. No y-mask (BYR | IMH).
__device__ __forceinline__ float phase2(
    const float* __restrict__ sq, int wb, int col, int r0) {
  const float GW[11] = {GW0, GW1, GW2, GW3, GW4, GW5,
                        GW4, GW3, GW2, GW1, GW0};
  v2f mu[4], ee[4];
  float e12[4];
#pragma unroll
  for (int o = 0; o < 4; ++o) {
    mu[o] = (v2f){0.f, 0.f};
    ee[o] = (v2f){0.f, 0.f};
    e12[o] = 0.f;
  }
#pragma unroll
  for (int i = 0; i < 15; ++i) {
    int slot = wb + r0 + i;        // <= 24+4+14 = 42
    if (slot >= WIN) slot -= WIN;  // one subtract suffices (< 2*WIN)
    const float* rowp = sq + slot * (5 * HSTR) + col;
    const v2f hp = (v2f){rowp[0 * HSTR], rowp[1 * HSTR]};  // ds_read2_b32
    const v2f hq = (v2f){rowp[2 * HSTR], rowp[3 * HSTR]};  // ds_read2_b32
    const float hsv = rowp[4 * HSTR];
    const int olo = (i - 10 < 0) ? 0 : i - 10;
    const int ohi = (i < 3) ? i : 3;
#pragma unroll
    for (int o = olo; o <= ohi; ++o) {  // row i is tap i-o of output o
      const float wt = GW[i - o];
      const v2f wv = (v2f){wt, wt};
      pkfma(mu[o], wv, hp);
      pkfma(ee[o], wv, hq);
      e12[o] = fmaf(wt, hsv, e12[o]);
    }
  }
  return (ssim_px(mu[0], ee[0], e12[0]) + ssim_px(mu[1], ee[1], e12[1])) +
         (ssim_px(mu[2], ee[2], e12[2]) + ssim_px(mu[3], ee[3], e12[3]));
}

__global__ __launch_bounds__(256, 4) void ssim_main(
    const float* __restrict__ gen, const float* __restrict__ ref,
    double* __restrict__ partial) {
  // Producer/consumer wave split, ONE barrier per chunk:
  //   waves 0-1 (128 thr): h-blur chunk c+1's 8 rows into the ring's free
  //     8-slot region (disjoint from the 18-row read window by WIN=26).
  //   waves 2-3 (128 thr): vertical blur + SSIM for chunk c's 8 output
  //     rows (4 rows per wave), reading the 18-row window.
  // Round-7 residual was 16 barriers/block with 2 waves idle during every
  // phase-1; this interval structure has 9 barriers and zero idle waves.
  __shared__ float s_q[WIN][5][HSTR];  // 33,800 B -> 4 blocks/CU
  float* const sq = &s_q[0][0][0];

  const int tid = threadIdx.x;
  const int bid = blockIdx.x;
  const int bx = bid & (NBX - 1);
  const int rem = bid >> 3;
  const int by = rem & (NBY - 1);
  const int plane = rem >> 3;
  const int x0 = bx * TX;
  const int Y0 = by * BYR;
  const float* gp = gen + (size_t)plane * (IMW * IMH);
  const float* rp = ref + (size_t)plane * (IMW * IMH);
  const bool ix = (bx >= 1) & (bx <= NBX - 2);

  const int col = tid & 63;
  // consumer wave's first output row within the chunk (wave2->0, wave3->4)
  const int r0 = __builtin_amdgcn_readfirstlane((tid >> 6 >= 3) ? 4 : 0);

  // Prologue: 18 h-rows [Y0-5, Y0+13) -> slots 0..17, split 16+2 so the
  // first call uses all 256 threads.
  hblur4(gp, rp, sq, x0, ix & (by > 0), 16, Y0 - 5, 0, tid);
  hblur4(gp, rp, sq, x0, ix, 2, Y0 + 11, 16, tid);
  __syncthreads();

  double acc = 0.0;
  int wbase = 0;   // read-window base: (8c) mod 26
  int sbase = 18;  // write base: (18+8c) mod 26 (always disjoint from window)
#pragma unroll 1
  for (int c = 0; c < MY; ++c) {
    if (tid < 128) {
      if (c < MY - 1) {
        // Stage chunk c+1's h-rows [Y0+13+8c, +8) into the free region.
        const int gy0 = Y0 + 13 + TY * c;
        hblur4(gp, rp, sq, x0, ix && (gy0 + TY <= IMH), TY, gy0, sbase, tid);
      }
    } else {
      // Consume chunk c: output rows Y0+8c .. +7.
      acc += (double)phase2(sq, wbase, col, r0);
    }
    __syncthreads();  // writes visible to next interval; reads protected by
                      // write/read slot disjointness within each interval
    wbase += TY;
    if (wbase >= WIN) wbase -= WIN;
    sbase += TY;
    if (sbase >= WIN) sbase -= WIN;
  }

  // Block reduction -> one deterministic double partial per block.
  // Ring is dead now (loop ends with a barrier): reuse it for partials.
#pragma unroll
  for (int off = 32; off > 0; off >>= 1) acc += __shfl_down(acc, off, 64);
  double* swsum = (double*)sq;
  if ((tid & 63) == 0) swsum[tid >> 6] = acc;
  __syncthreads();
  if (tid == 0) partial[bid] = swsum[0] + swsum[1] + swsum[2] + swsum[3];
}

__global__ void ssim_reduce(const double* __restrict__ partial,
                            float* __restrict__ out) {
  const int tid = threadIdx.x;
  double s = 0.0;
  // 6144 = 24 * 256 partials, fixed-order per thread (deterministic).
  for (int i = tid; i < NBLOCKS; i += 256) s += partial[i];
#pragma unroll
  for (int off = 32; off > 0; off >>= 1) s += __shfl_down(s, off, 64);
  __shared__ double sd[4];
  if ((tid & 63) == 0) sd[tid >> 6] = s;
  __syncthreads();
  if (tid == 0) {
    const double npix = (double)NPLANES * (double)IMW * (double)IMH;
    out[0] = (float)(1.0 - (sd[0] + sd[1] + sd[2] + sd[3]) / npix);
  }
}

extern "C" void kernel_launch(void* const* d_in, const int* in_sizes, int n_in,
                              void* d_out, int out_size, void* d_ws, size_t ws_size,
                              hipStream_t stream) {
  (void)in_sizes; (void)n_in; (void)out_size; (void)ws_size;
  const float* gen = (const float*)d_in[0];
  const float* ref = (const float*)d_in[1];
  double* partial = (double*)d_ws;  // NBLOCKS doubles; every slot written each call
  ssim_main<<<NBLOCKS, 256, 0, stream>>>(gen, ref, partial);
  ssim_reduce<<<1, 256, 0, stream>>>(partial, (float*)d_out);
}

// Round 9
// 299.111 us; speedup vs baseline: 3.4924x; 1.0892x over previous
//
#include <hip/hip_runtime.h>

typedef float v2f __attribute__((ext_vector_type(2)));

#define TY 8                  // output rows per chunk
#define WIN 18                // private ring rows (TY + 10)
#define CST 33                // col stride (32 cols + 1 pad)
#define RST (5 * CST)         // ring row stride = 165 dwords (165%32=5)
#define SWV (WIN * RST)       // per-wave ring = 2970 dwords = 11,880 B
#define IMW 512
#define IMH 512
#define NPLANES 96            // 32 * 3
#define NSX 16                // 32-col strips
#define NSEG 2                // 256-row segments
#define NCH 32                // chunks per segment (256/8)
#define NWAVES (NSX * NSEG * NPLANES)  // 3072
#define NBLOCKS (NWAVES / 4)           // 768 = 3 blocks/CU, ALL resident

// Gaussian(sigma=1.5, ws=11), double-computed, fp32-rounded.
#define GW0 0.00102838f
#define GW1 0.00759877f
#define GW2 0.03600077f
#define GW3 0.10936069f
#define GW4 0.21300553f
#define GW5 0.26601172f

__device__ __forceinline__ void pkfma(v2f& acc, v2f a, v2f b) {
  asm("v_pk_fma_f32 %0, %1, %2, %0" : "+v"(acc) : "v"(a), "v"(b));
}
__device__ __forceinline__ v2f pkmul(v2f a, v2f b) {
  v2f d;
  asm("v_pk_mul_f32 %0, %1, %2" : "=v"(d) : "v"(a), "v"(b));
  return d;
}

// ---- h-phase: horizontal 11-tap blur of `nrows` rows into the wave's
// PRIVATE ring. Lane role: hr = lane>>3 (row), xs = (lane&7)*4 (4 outputs).
// No per-thread aggregates (r4-r6 scratch lesson): float4 -> v2f P[14]
// with compile-time indices. Window cols xs-5..xs+8 = P[0..13]; loads
// cover [xs-8, xs+12) as 5 aligned float4 per image.
__device__ __forceinline__ void hblur(
    const float* __restrict__ gp, const float* __restrict__ rp,
    float* __restrict__ sq, int x0, bool fast, int nrows, int gy0,
    int slot0, int hr, int xs) {
  if (hr >= nrows) return;
  const float GW[11] = {GW0, GW1, GW2, GW3, GW4, GW5,
                        GW4, GW3, GW2, GW1, GW0};
  const int gy = gy0 + hr;
  int slot = slot0 + hr;
  if (slot >= WIN) slot -= WIN;  // slot0<=16, hr<=7 -> one subtract
  const int xbase = x0 + xs - 8;  // loaded cols [xbase, xbase+20)
  const float* grow = gp + (size_t)gy * IMW;
  const float* rrow = rp + (size_t)gy * IMW;

  v2f P[14];  // transformed (g,r); window position p <-> loaded col p+3
#define PUT1(idx, gc, rc)                                                    \
  do {                                                                       \
    if ((idx) >= 3 && (idx) <= 16)                                           \
      P[(idx) - 3] = (v2f){fmaf(0.5f, (gc), 0.5f), fmaf(0.5f, (rc), 0.5f)};  \
  } while (0)
  if (fast) {
#pragma unroll
    for (int k = 0; k < 5; ++k) {
      const float4 g4 = *(const float4*)(grow + xbase + 4 * k);
      const float4 r4 = *(const float4*)(rrow + xbase + 4 * k);
      PUT1(4 * k + 0, g4.x, r4.x);
      PUT1(4 * k + 1, g4.y, r4.y);
      PUT1(4 * k + 2, g4.z, r4.z);
      PUT1(4 * k + 3, g4.w, r4.w);
    }
  } else {
    const bool rowok = (gy >= 0) & (gy < IMH);
#pragma unroll
    for (int k = 0; k < 5; ++k) {
      const int c = xbase + 4 * k;
      const bool ok = rowok && (c >= 0) && (c < IMW);
      float4 g4 = make_float4(-1.f, -1.f, -1.f, -1.f);
      float4 r4 = g4;  // transform maps -1 -> 0 (matches conv zero padding)
      if (ok) {
        g4 = *(const float4*)(grow + c);
        r4 = *(const float4*)(rrow + c);
      }
      PUT1(4 * k + 0, g4.x, r4.x);
      PUT1(4 * k + 1, g4.y, r4.y);
      PUT1(4 * k + 2, g4.z, r4.z);
      PUT1(4 * k + 3, g4.w, r4.w);
    }
  }
#undef PUT1

  v2f accP[4], accQ[4];
  float accS[4];
#pragma unroll
  for (int o = 0; o < 4; ++o) {
    accP[o] = (v2f){0.f, 0.f};
    accQ[o] = (v2f){0.f, 0.f};
    accS[o] = 0.f;
  }

  // Output o (col xs+o) uses window positions p = o..o+10.
#pragma unroll
  for (int p = 0; p < 14; ++p) {
    const v2f pv = P[p];
    const v2f qv = pkmul(pv, pv);
    const float sv = pv.x * pv.y;
    const int olo = (p - 10 < 0) ? 0 : p - 10;
    const int ohi = (p < 3) ? p : 3;
#pragma unroll
    for (int o = olo; o <= ohi; ++o) {
      const float wt = GW[p - o];
      const v2f wv = (v2f){wt, wt};
      pkfma(accP[o], wv, pv);
      pkfma(accQ[o], wv, qv);
      accS[o] = fmaf(wt, sv, accS[o]);
    }
  }

  // One VGPR address, all 5 planes via immediate dword offsets q*33+o
  // (max 135 < 256 -> ds_write2_b32 pairs). Banks: (5*slot+4*cg+o) mod 32
  // over 8x8 lanes -> exactly 2 lanes/bank (free, m136).
  float* dst = sq + slot * RST + xs;
#pragma unroll
  for (int o = 0; o < 4; ++o) dst[0 * CST + o] = accP[o].x;
#pragma unroll
  for (int o = 0; o < 4; ++o) dst[1 * CST + o] = accP[o].y;
#pragma unroll
  for (int o = 0; o < 4; ++o) dst[2 * CST + o] = accQ[o].x;
#pragma unroll
  for (int o = 0; o < 4; ++o) dst[3 * CST + o] = accQ[o].y;
#pragma unroll
  for (int o = 0; o < 4; ++o) dst[4 * CST + o] = accS[o];
}

__device__ __forceinline__ float ssim_px(v2f mu, v2f ee, float e12) {
  const float C1 = 6.5025f, C2 = 58.5225f;
  const float mu1 = mu.x, mu2 = mu.y, e1 = ee.x, e2 = ee.y;
  const float m12 = mu1 * mu2;
  const float m1s = mu1 * mu1;
  const float m2s = mu2 * mu2;
  const float num = (2.f * m12 + C1) * (2.f * (e12 - m12) + C2);
  const float den = (m1s + m2s + C1) * ((e1 - m1s) + (e2 - m2s) + C2);
  return __fdividef(num, den);
}

// ---- v-phase: vertical 11-tap blur + SSIM for 4 output rows per lane,
// streaming 14 ring rows. Lane role: col = lane&31, r0 = (lane>>5)*4.
// One VGPR address per row; planes via immediate offsets (q*33, max 132).
// Read banks: 32 stride-1 cols x 2 groups -> exactly 2-way (free).
__device__ __forceinline__ float vchunk(
    const float* __restrict__ sq, int wb, int col, int r0) {
  const float GW[11] = {GW0, GW1, GW2, GW3, GW4, GW5,
                        GW4, GW3, GW2, GW1, GW0};
  v2f mu[4], ee[4];
  float e12[4];
#pragma unroll
  for (int o = 0; o < 4; ++o) {
    mu[o] = (v2f){0.f, 0.f};
    ee[o] = (v2f){0.f, 0.f};
    e12[o] = 0.f;
  }
#pragma unroll
  for (int i = 0; i < 14; ++i) {
    int slot = wb + r0 + i;        // <= 16+4+13 = 33
    if (slot >= WIN) slot -= WIN;  // one subtract suffices (< 2*WIN)
    const float* rowp = sq + slot * RST + col;
    const v2f hp = (v2f){rowp[0 * CST], rowp[1 * CST]};  // ds_read2_b32
    const v2f hq = (v2f){rowp[2 * CST], rowp[3 * CST]};  // ds_read2_b32
    const float hsv = rowp[4 * CST];
    const int olo = (i - 10 < 0) ? 0 : i - 10;
    const int ohi = (i < 3) ? i : 3;
#pragma unroll
    for (int o = olo; o <= ohi; ++o) {  // row i is tap i-o of output o
      const float wt = GW[i - o];
      const v2f wv = (v2f){wt, wt};
      pkfma(mu[o], wv, hp);
      pkfma(ee[o], wv, hq);
      e12[o] = fmaf(wt, hsv, e12[o]);
    }
  }
  return (ssim_px(mu[0], ee[0], e12[0]) + ssim_px(mu[1], ee[1], e12[1])) +
         (ssim_px(mu[2], ee[2], e12[2]) + ssim_px(mu[3], ee[3], e12[3]));
}

__global__ __launch_bounds__(256, 3) void ssim_main(
    const float* __restrict__ gen, const float* __restrict__ ref,
    double* __restrict__ partial) {
  // WAVE-PRIVATE tiles: each wave owns a 32-col x 256-row strip and a
  // private 18-row LDS ring. Producer and consumer are the SAME wave, so
  // there are ZERO __syncthreads in the kernel: in-wave LDS ops execute in
  // order at the DS unit; the compiler's lgkmcnt waits cover data return.
  // (r0-r8 evidence: barriers fragmented wave instruction streams into
  // ~250-instr slices -> 104 us of stall at 48% VALUBusy. This removes the
  // fragmentation instead of trying to overlap it.)
  // 768 blocks x 47,520 B LDS = 3 blocks/CU -> the ENTIRE grid is
  // co-resident in one generation (12 waves/CU, no dispatch tail).
  // y-redundancy: 266 h-rows per 256 outputs = 1.04 (best yet).
  __shared__ float ring[4][SWV];  // 47,520 B

  const int tid = threadIdx.x;
  const int wv = tid >> 6;
  const int lane = tid & 63;
  const int wid = (blockIdx.x << 2) | wv;
  const int plane = wid >> 5;        // 32 wave-tasks per plane
  const int rem = wid & 31;
  const int sx = rem & 15;
  const int seg = rem >> 4;
  const int x0 = sx * 32;
  const int Y0 = seg * 256;
  const float* gp = gen + (size_t)plane * (IMW * IMH);
  const float* rp = ref + (size_t)plane * (IMW * IMH);
  float* const sq = &ring[wv][0];
  const bool fx = (sx >= 1) & (sx <= NSX - 2);

  const int hr = lane >> 3;        // h-phase: row 0..7
  const int xs = (lane & 7) * 4;   // h-phase: 4-col run
  const int col = lane & 31;       // v-phase: column
  const int r0 = (lane >> 5) * 4;  // v-phase: first of 4 output rows

  // Prologue: fill ring with h-rows [Y0-5, Y0+13) -> slots 0..17.
  hblur(gp, rp, sq, x0, fx & (seg > 0), 8, Y0 - 5, 0, hr, xs);
  hblur(gp, rp, sq, x0, fx, 8, Y0 + 3, 8, hr, xs);
  hblur(gp, rp, sq, x0, fx, 2, Y0 + 11, 16, hr, xs);

  double acc = 0.0;
  int wb = 0;  // window base: (8c) mod 18
#pragma unroll 1
  for (int c = 0; c < NCH; ++c) {
    // Consume chunk c: output rows Y0+8c..+7 from ring window wb..wb+17.
    acc += (double)vchunk(sq, wb, col, r0);
    if (c < NCH - 1) {
      // Produce chunk c+1's h-rows [Y0+13+8c, +8) over the 8 oldest slots
      // (base = wb). Same wave: no barrier; DS unit preserves read->write
      // order, ring disjointness does the rest.
      const int gy0 = Y0 + 13 + TY * c;
      hblur(gp, rp, sq, x0, fx && (gy0 + TY <= IMH), TY, gy0, wb, hr, xs);
    }
    wb += TY;
    if (wb >= WIN) wb -= WIN;
  }

  // Wave-level reduction only (waves never interact): one double per wave.
#pragma unroll
  for (int off = 32; off > 0; off >>= 1) acc += __shfl_down(acc, off, 64);
  if (lane == 0) partial[wid] = acc;
}

__global__ void ssim_reduce(const double* __restrict__ partial,
                            float* __restrict__ out) {
  const int tid = threadIdx.x;
  double s = 0.0;
  // 3072 = 12 * 256 partials, fixed-order per thread (deterministic).
  for (int i = tid; i < NWAVES; i += 256) s += partial[i];
#pragma unroll
  for (int off = 32; off > 0; off >>= 1) s += __shfl_down(s, off, 64);
  __shared__ double sd[4];
  if ((tid & 63) == 0) sd[tid >> 6] = s;
  __syncthreads();
  if (tid == 0) {
    const double npix = (double)NPLANES * (double)IMW * (double)IMH;
    out[0] = (float)(1.0 - (sd[0] + sd[1] + sd[2] + sd[3]) / npix);
  }
}

extern "C" void kernel_launch(void* const* d_in, const int* in_sizes, int n_in,
                              void* d_out, int out_size, void* d_ws, size_t ws_size,
                              hipStream_t stream) {
  (void)in_sizes; (void)n_in; (void)out_size; (void)ws_size;
  const float* gen = (const float*)d_in[0];
  const float* ref = (const float*)d_in[1];
  double* partial = (double*)d_ws;  // NWAVES doubles; every slot written each call
  ssim_main<<<NBLOCKS, 256, 0, stream>>>(gen, ref, partial);
  ssim_reduce<<<1, 256, 0, stream>>>(partial, (float*)d_out);
}